// Round 3
// baseline (233.121 us; speedup 1.0000x reference)
//
#include <hip/hip_runtime.h>

typedef unsigned short u16;
typedef unsigned int u32;
typedef __attribute__((ext_vector_type(8))) short bf16x8;
typedef __attribute__((ext_vector_type(4))) float f32x4;

#define DIM 256
#define NOUT 512
#define MROWS 32768
#define NEDGE (256*128*128)
#define PARAM_SZ (32768*512)

__device__ __forceinline__ u16 f2bf(float f) {
    u32 x = __float_as_uint(f);
    u32 r = (x + 0x7FFFu + ((x >> 16) & 1u)) >> 16;   // round-to-nearest-even
    return (u16)r;
}

// ---------------- W transpose+convert: W[k][n] fp32 (256x512) -> Wt[n][k] bf16 (512x256) ----
__global__ __launch_bounds__(1024) void transpose_kernel(const float* __restrict__ W,
                                                         u16* __restrict__ Wt) {
    __shared__ u16 tile[32][33];
    int n0 = blockIdx.x * 32;   // N: 512 -> 16 blocks
    int k0 = blockIdx.y * 32;   // K: 256 -> 8 blocks
    int tx = threadIdx.x, ty = threadIdx.y;
    tile[ty][tx] = f2bf(W[(k0 + ty) * NOUT + n0 + tx]);
    __syncthreads();
    Wt[(n0 + ty) * DIM + k0 + tx] = tile[tx][ty];
}

// ---------------- Edge kernel: radial (fp32) + coord_diff (fp32) ----------------
__global__ __launch_bounds__(256) void edge_kernel(const int* __restrict__ edges,
                                                   const float* __restrict__ x,
                                                   float* __restrict__ radial_out,
                                                   float* __restrict__ cd_out) {
    int e = blockIdx.x * 256 + threadIdx.x;
    int row = edges[e];
    int col = edges[NEDGE + e];
    float ax = x[row * 3 + 0], ay = x[row * 3 + 1], az = x[row * 3 + 2];
    float bx = x[col * 3 + 0], by = x[col * 3 + 1], bz = x[col * 3 + 2];
    float dx = ax - bx, dy = ay - by, dz = az - bz;
    float radial = dx * dx + dy * dy + dz * dz;
    float denom = sqrtf(radial + 1e-8f) + 1.0f;   // norm + norm_constant(1.0)
    radial_out[e] = radial;

    // repack coord_diff [E,3] through LDS so global writes are dense/coalesced
    __shared__ float buf[768];
    buf[threadIdx.x * 3 + 0] = dx / denom;   // stride-3: 2-way bank alias (free)
    buf[threadIdx.x * 3 + 1] = dy / denom;
    buf[threadIdx.x * 3 + 2] = dz / denom;
    __syncthreads();
    size_t base = (size_t)blockIdx.x * 768;
    cd_out[base + threadIdx.x]       = buf[threadIdx.x];
    cd_out[base + 256 + threadIdx.x] = buf[256 + threadIdx.x];
    cd_out[base + 512 + threadIdx.x] = buf[512 + threadIdx.x];
}

// ---------------- GEMM: parameters = h @ W + b  (h built on the fly, fp32 out) ----------
// Block = 256 threads (4 waves), M-tile = 64 rows. Wave w: cols [w*128,w*128+128),
// 4 M-subtiles x 8 N-subtiles of 16x16x32 MFMA -> 128 acc VGPRs; B-frag reused x4.
__global__ __launch_bounds__(256, 2) void gemm_kernel(const int* __restrict__ cats,
                                                      const float* __restrict__ charges,
                                                      const float* __restrict__ nmask,
                                                      const float* __restrict__ emb,
                                                      const u16* __restrict__ Wt,
                                                      const float* __restrict__ bias,
                                                      float* __restrict__ out) {
    __shared__ u16 h_lds[64][DIM + 8];   // +8 pad: row stride 528B
    const int m0 = blockIdx.x * 64;
    const int tid = threadIdx.x;

    // Stage h tile (64 rows x 256 cols) as bf16: 1024 (row, 16-col-chunk) tasks
    for (int t = tid; t < 1024; t += 256) {
        int r = t >> 4;
        int c0 = (t & 15) * 16;
        int m = m0 + r;
        float mask = nmask[m];
        int ebase = cats[m] * (DIM - 1);
        #pragma unroll
        for (int i = 0; i < 16; ++i) {
            int c = c0 + i;
            float v = (c == 0) ? charges[m] : emb[ebase + c - 1];
            h_lds[r][c] = f2bf(v * mask);
        }
    }
    __syncthreads();

    const int wave = tid >> 6;
    const int lane = tid & 63;
    const int lrow = lane & 15;   // A row / B col / D col
    const int quad = lane >> 4;   // k-group for A/B, row-group for D
    const int nbase = wave * 128;

    f32x4 acc[4][8];
    #pragma unroll
    for (int ms = 0; ms < 4; ++ms)
        #pragma unroll
        for (int nt = 0; nt < 8; ++nt) acc[ms][nt] = (f32x4)(0.0f);

    #pragma unroll
    for (int k0 = 0; k0 < DIM; k0 += 32) {
        bf16x8 a[4];
        #pragma unroll
        for (int ms = 0; ms < 4; ++ms)
            a[ms] = *(const bf16x8*)&h_lds[ms * 16 + lrow][k0 + quad * 8];
        #pragma unroll
        for (int nt = 0; nt < 8; ++nt) {
            bf16x8 bfr = *(const bf16x8*)&Wt[(size_t)(nbase + nt * 16 + lrow) * DIM + k0 + quad * 8];
            #pragma unroll
            for (int ms = 0; ms < 4; ++ms)
                acc[ms][nt] = __builtin_amdgcn_mfma_f32_16x16x32_bf16(a[ms], bfr, acc[ms][nt], 0, 0, 0);
        }
    }

    // Epilogue: D[row=quad*4+r][col=lrow] per 16x16 tile; + bias, store fp32
    #pragma unroll
    for (int nt = 0; nt < 8; ++nt) {
        int n = nbase + nt * 16 + lrow;
        float bv = bias[n];
        #pragma unroll
        for (int ms = 0; ms < 4; ++ms)
            #pragma unroll
            for (int r = 0; r < 4; ++r)
                out[(size_t)(m0 + ms * 16 + quad * 4 + r) * NOUT + n] = acc[ms][nt][r] + bv;
    }
}

extern "C" void kernel_launch(void* const* d_in, const int* in_sizes, int n_in,
                              void* d_out, int out_size, void* d_ws, size_t ws_size,
                              hipStream_t stream) {
    const float* x       = (const float*)d_in[0];   // [32768*3] fp32
    const int*   cats    = (const int*)d_in[1];     // [32768] int32
    const float* charges = (const float*)d_in[2];   // [32768] fp32
    const int*   edges   = (const int*)d_in[3];     // [2*E] int32
    const float* nmask   = (const float*)d_in[4];   // [32768] fp32 (all ones)
    // d_in[5] edge_mask: unused by reference
    const float* emb     = (const float*)d_in[6];   // [100*255] fp32
    const float* W       = (const float*)d_in[7];   // [256*512] fp32
    const float* bias    = (const float*)d_in[8];   // [512] fp32

    float* out    = (float*)d_out;
    float* params = out;                          // 16,777,216 fp32
    float* radial = out + PARAM_SZ;               // 4,194,304 fp32
    float* cd     = out + PARAM_SZ + NEDGE;       // 12,582,912 fp32
    u16*   Wt     = (u16*)d_ws;                   // 512*256 bf16 = 256 KB scratch

    transpose_kernel<<<dim3(16, 8), dim3(32, 32), 0, stream>>>(W, Wt);
    edge_kernel<<<NEDGE / 256, 256, 0, stream>>>(edges, x, radial, cd);
    gemm_kernel<<<MROWS / 64, 256, 0, stream>>>(cats, charges, nmask, emb, Wt, bias, params);
}